// Round 16
// baseline (353.081 us; speedup 1.0000x reference)
//
#include <hip/hip_runtime.h>

#define N_NODES 200000
#define N_EDGES 6400000

constexpr int BSHIFT = 9;                      // 512 nodes per bucket
constexpr int NBUCK  = (N_NODES + 511) / 512;  // 391
constexpr int CHUNK  = 16384;
constexpr int NCHUNK = (N_EDGES + CHUNK - 1) / CHUNK;  // 391
constexpr int MAXBUCK = 18432;                 // fixed slot per bucket
constexpr int SEGSTRIDE = 2052;                // 2048 bins + end sentinel + pad
constexpr int SEGMAX = 1536;                   // staged edges per (b,Q,q); lambda=1024

// ---- edge index load helper: handles int32 or int64 storage ----
__device__ __forceinline__ int ld_edge(const void* ei, int is64, int idx) {
    return is64 ? (int)((const long long*)ei)[idx] : ((const int*)ei)[idx];
}

// fused init: zero accG (all blocks) + iota cursor + int64 detect (block 0)
__global__ void k_init(int* __restrict__ cursor, const unsigned int* __restrict__ ei,
                       int* __restrict__ flag, int* __restrict__ accG) {
    __shared__ int nz;
    int i = blockIdx.x * blockDim.x + threadIdx.x;
    if (i < N_NODES * 16) accG[i] = 0;
    if (blockIdx.x == 0) {
        int t = threadIdx.x;
        for (int j = t; j < NBUCK; j += 256) cursor[j] = j * MAXBUCK;
        if (t == 0) nz = 0;
        __syncthreads();
        if (ei[2 * t + 1] != 0u) atomicOr(&nz, 1);
        __syncthreads();
        if (t == 0) *flag = nz ? 0 : 1;
    }
}

// level-1: bin a 16K-edge chunk by dst-bucket. Each thread holds its 16
// edges in REGISTERS (static unroll) -> src/dst each read exactly once.
// Staged word packs (q<<27)|(local_dst<<18)|src; contiguous runs written
// into the bucket's FIXED slot.
__global__ void __launch_bounds__(1024)
k_binscatter(const void* __restrict__ ei, const int* __restrict__ flag,
             int* __restrict__ bucketCursor, unsigned int* __restrict__ bin) {
    __shared__ int hist[NBUCK];
    __shared__ int pref[NBUCK + 1];
    __shared__ int cur[NBUCK];
    __shared__ int gb[NBUCK];
    __shared__ int sc[512];
    __shared__ unsigned int stage[CHUNK];
    const int is64 = *flag;
    int b = blockIdx.x, t = threadIdx.x;
    int e0 = b * CHUNK;
    int n = min(CHUNK, N_EDGES - e0);
    for (int i = t; i < NBUCK; i += 1024) hist[i] = 0;
    // load my 16 edges into registers (coalesced, stride-1024)
    int sd[16], ss[16];
#pragma unroll
    for (int j = 0; j < 16; ++j) {
        int idx = t + (j << 10);
        if (idx < n) {
            ss[j] = ld_edge(ei, is64, e0 + idx);
            sd[j] = ld_edge(ei, is64, N_EDGES + e0 + idx);
        } else {
            ss[j] = -1; sd[j] = -1;
        }
    }
    __syncthreads();
    // pass A: per-chunk bucket histogram (from registers)
#pragma unroll
    for (int j = 0; j < 16; ++j)
        if (sd[j] >= 0) atomicAdd(&hist[sd[j] >> BSHIFT], 1);
    __syncthreads();
    // scan 512 entries (threads 0-255 work, all barrier)
    if (t < 256) {
        sc[t]       = (t < NBUCK)       ? hist[t]       : 0;
        sc[t + 256] = (t + 256 < NBUCK) ? hist[t + 256] : 0;
    }
    __syncthreads();
    for (int off = 1; off < 512; off <<= 1) {
        int a0 = 0, a1 = 0;
        if (t < 256) {
            a0 = (t >= off) ? sc[t - off] : 0;
            a1 = sc[t + 256 - off];
        }
        __syncthreads();
        if (t < 256) { sc[t] += a0; sc[t + 256] += a1; }
        __syncthreads();
    }
    for (int i = t; i < NBUCK; i += 1024) {
        int excl = sc[i] - hist[i];
        pref[i] = excl;
        cur[i] = excl;
    }
    if (t == 0) pref[NBUCK] = n;
    __syncthreads();
    // pass B: scatter packed (q<<27)|(local_d<<18)|src into LDS stage
#pragma unroll
    for (int j = 0; j < 16; ++j) {
        if (sd[j] >= 0) {
            int bk = sd[j] >> BSHIFT;
            unsigned int q = (unsigned int)ss[j] / 50000u;
            int p = atomicAdd(&cur[bk], 1);
            stage[p] = (q << 27) | ((unsigned int)(sd[j] & 511) << 18) | (unsigned int)ss[j];
        }
    }
    __syncthreads();
    // reserve global ranges in fixed slots, one atomic per non-empty bucket
    for (int i = t; i < NBUCK; i += 1024) {
        int c = hist[i];
        gb[i] = c ? atomicAdd(&bucketCursor[i], c) : 0;
    }
    __syncthreads();
    // write-out: wave w copies buckets w, w+16, ... (contiguous runs);
    // clamp to slot end (safety, never expected to trigger)
    int wave = t >> 6, lane = t & 63;
    for (int i = wave; i < NBUCK; i += 16) {
        int c = hist[i];
        if (!c) continue;
        int gg = gb[i];
        int room = (i + 1) * MAXBUCK - gg;
        int lim = min(c, max(room, 0));
        int pp = pref[i];
        for (int j = lane; j < lim; j += 64) bin[gg + j] = stage[pp + j];
    }
}

// level-2: one block per bucket, 1024 threads. Counting-sort the bucket's
// edges by key (q<<9)|RANK where rank = degree-sorted position of dst
// within its q (so k_agg waves see 16 near-equal-length runs -> no
// divergence waste). Emits u16 rowptr (by rank), perm (rank->dst), dinv.
// Payload written back as src<<4 (pre-shifted hs offset).
__global__ void __launch_bounds__(1024)
k_bucketsort(const int* __restrict__ bucketCursor, unsigned int* __restrict__ bin,
             float* __restrict__ dinv, unsigned short* __restrict__ seg16,
             unsigned short* __restrict__ permG) {
    __shared__ int cnt[2048];        // by (q<<9)|dst
    __shared__ int cntP[2048];       // by (q<<9)|rank
    __shared__ int cur[2048];        // rowptr by rank (mutated in pass B)
    __shared__ int tsum[1024];
    __shared__ int dhist[256];       // 4 q x 64 degree bins
    __shared__ unsigned short rank[2048];  // (q<<9)|dst -> rank
    __shared__ unsigned short perm[2048];  // (q<<9)|rank -> dst
    __shared__ unsigned int payload[MAXBUCK];
    int b = blockIdx.x, t = threadIdx.x;
    int base = b * MAXBUCK;
    int n = min(bucketCursor[b] - base, MAXBUCK);
    cnt[t] = 0; cnt[t + 1024] = 0;
    if (t < 256) dhist[t] = 0;
    __syncthreads();
    // pass A: histogram over 2048 (q, dst) bins
    for (int i = t; i < n; i += 1024) {
        unsigned int u = bin[base + i];
        int key = (int)((u >> 27) << 9) | (int)((u >> 18) & 511u);
        atomicAdd(&cnt[key], 1);
    }
    __syncthreads();
    // degree histogram per q (64 clamped degree bins)
    for (int i = t; i < 2048; i += 1024) {
        int dg = min(cnt[i], 63);
        atomicAdd(&dhist[((i >> 9) << 6) | dg], 1);
    }
    __syncthreads();
    // exclusive scan within each q's 64 degree bins (serial, 4 threads)
    if (t < 4) {
        int acc = 0;
        for (int j = 0; j < 64; ++j) {
            int idx = (t << 6) | j;
            int c = dhist[idx]; dhist[idx] = acc; acc += c;
        }
    }
    __syncthreads();
    // assign degree-sorted ranks; build perm and rank-ordered counts
    for (int i = t; i < 2048; i += 1024) {
        int dg = min(cnt[i], 63);
        int q = i >> 9;
        int r = atomicAdd(&dhist[(q << 6) | dg], 1);
        rank[i] = (unsigned short)r;
        perm[(q << 9) | r] = (unsigned short)(i & 511);
        cntP[(q << 9) | r] = cnt[i];
    }
    __syncthreads();
    // scan 2048 over cntP: serial-2 per thread + Hillis-Steele over 1024 sums
    int b0 = t * 2;
    int s = cntP[b0] + cntP[b0 + 1];
    tsum[t] = s;
    __syncthreads();
    int v = s;
    for (int off = 1; off < 1024; off <<= 1) {
        int add = (t >= off) ? tsum[t - off] : 0;
        __syncthreads();
        tsum[t] += add;
        __syncthreads();
    }
    int run = tsum[t] - v;  // exclusive prefix of this thread's pair
    cur[b0] = run;
    cur[b0 + 1] = run + cntP[b0];
    __syncthreads();
    // write u16 rowptr-by-rank + perm + sentinel + dinv
    for (int i = t; i < 2048; i += 1024) {
        seg16[b * SEGSTRIDE + i] = (unsigned short)cur[i];
        permG[b * 2048 + i] = perm[i];
    }
    if (t == 0) seg16[b * SEGSTRIDE + 2048] = (unsigned short)n;
    int node0 = b << BSHIFT;
    if (t < 512) {
        int node = node0 + t;
        if (node < N_NODES) {
            int deg = cnt[t] + cnt[512 + t] + cnt[1024 + t] + cnt[1536 + t];
            dinv[node] = rsqrtf((float)deg + 1.0f);
        }
    }
    __syncthreads();
    // pass B: scatter src<<4 into payload by rank-order position
    for (int i = t; i < n; i += 1024) {
        unsigned int u = bin[base + i];
        int korig = (int)((u >> 27) << 9) | (int)((u >> 18) & 511u);
        int key = (int)((u >> 27) << 9) | (int)rank[korig];
        int p = atomicAdd(&cur[key], 1);
        if (p < MAXBUCK) payload[p] = (u & 0x3FFFFu) << 4;
    }
    __syncthreads();
    // coalesced in-place write-back (sorted by (q, rank))
    for (int i = t; i < n; i += 1024) bin[base + i] = payload[i];
}

// hs = dinv[i] * (x @ W), padded to stride 16 (one 64B line per row).
template <int FIN, int FOUT, int SIN>
__global__ void k_xw(const float* xin, const float* __restrict__ W,
                     const float* __restrict__ dinv, float* hs) {
    __shared__ float sW[FIN * FOUT];
    int t = threadIdx.x;
    if (t < FIN * FOUT) sW[t] = W[t];
    __syncthreads();
    int i = blockIdx.x * 256 + t;
    if (i >= N_NODES) return;
    float xi[FIN];
#pragma unroll
    for (int k = 0; k < FIN; ++k) xi[k] = xin[i * SIN + k];
    float di = dinv[i];
    float o[FOUT];
#pragma unroll
    for (int j = 0; j < FOUT; ++j) {
        float acc = 0.f;
#pragma unroll
        for (int k = 0; k < FIN; ++k) acc += xi[k] * sW[k * FOUT + j];
        o[j] = di * acc;
    }
#pragma unroll
    for (int j = 0; j < FOUT; ++j) hs[i * 16 + j] = o[j];
}

// Fused boundary kernel: x' = relu(dinv*(accG + hs_prev) + biasPrev);
// hs_next = dinv * (x' @ Wnext) -> B. Re-zeros accG for the next layer.
template <int FIN, int FOUT>
__global__ void k_fx(float* __restrict__ B, float* __restrict__ accG,
                     const float* __restrict__ dinv,
                     const float* __restrict__ biasPrev,
                     const float* __restrict__ Wnext) {
    __shared__ float sW[FIN * FOUT];
    __shared__ float sb[FIN];
    int t = threadIdx.x;
    if (t < FIN * FOUT) sW[t] = Wnext[t];
    if (t < FIN) sb[t] = biasPrev[t];
    __syncthreads();
    int i = blockIdx.x * 256 + t;
    if (i >= N_NODES) return;
    float di = dinv[i];
    float xi[FIN];
#pragma unroll
    for (int k = 0; k < FIN; ++k) {
        float v = di * (accG[i * 16 + k] + B[i * 16 + k]) + sb[k];
        xi[k] = fmaxf(v, 0.f);
    }
#pragma unroll
    for (int c = 0; c < 16; ++c) accG[i * 16 + c] = 0.f;
    float o[FOUT];
#pragma unroll
    for (int j = 0; j < FOUT; ++j) {
        float acc = 0.f;
#pragma unroll
        for (int k = 0; k < FIN; ++k) acc += xi[k] * sW[k * FOUT + j];
        o[j] = di * acc;
    }
#pragma unroll
    for (int j = 0; j < FOUT; ++j) B[i * 16 + j] = o[j];
}

// One block per (bucket, quarter, q). q = blk&3 -> XCD-pinned 3.2 MB src
// window; bin segment staged to LDS; payload pre-shifted src<<4. Runs are
// now degree-SORTED (rank order) so all 16 dsts in a wave have near-equal
// length -> no exec-mask waste. Flush: node = node0 + perm[rank]; still
// one unsafeAtomicAdd per dst with 16 consecutive lanes = one line RMW.
__global__ void __launch_bounds__(512)
k_agg(const unsigned short* __restrict__ seg16, const unsigned short* __restrict__ permG,
      const unsigned int* __restrict__ bin, const float* __restrict__ hs,
      float* __restrict__ accG) {
    __shared__ unsigned short s_sr[132];
    __shared__ unsigned short s_perm[128];
    __shared__ unsigned int s_bin[SEGMAX];
    int blk = blockIdx.x;
    int q = blk & 3;
    int Q = (blk >> 2) & 3;
    int b = blk >> 4;
    int t = threadIdx.x;
    int base = b * MAXBUCK;
    const unsigned short* sr = seg16 + b * SEGSTRIDE + (q << 9) + (Q << 7);
    if (t < 129) s_sr[t] = sr[t];
    if (t >= 256 && t < 384) s_perm[t - 256] = permG[b * 2048 + (q << 9) + (Q << 7) + (t - 256)];
    __syncthreads();
    int s0 = (int)s_sr[0];
    int nseg = (int)s_sr[128] - s0;
    bool staged = (nseg <= SEGMAX);
    if (staged) {
        for (int i = t; i < nseg; i += 512) s_bin[i] = bin[base + s0 + i];
    }
    __syncthreads();
    int g = t >> 4, f = t & 15;
    int dd0 = g << 2;
    int r0 = (int)s_sr[dd0 + 0], r1 = (int)s_sr[dd0 + 1], r2 = (int)s_sr[dd0 + 2];
    int r3 = (int)s_sr[dd0 + 3], r4 = (int)s_sr[dd0 + 4];
    int n0 = r1 - r0, n1 = r2 - r1, n2 = r3 - r2, n3 = r4 - r3;
    float a0 = 0.f, a1 = 0.f, a2 = 0.f, a3 = 0.f;
    int m = max(max(n0, n1), max(n2, n3));
    if (staged) {
        int o0 = r0 - s0, o1 = r1 - s0, o2 = r2 - s0, o3 = r3 - s0;
#pragma unroll 2
        for (int k = 0; k < m; k += 2) {
            float t00 = 0.f, t01 = 0.f, t10 = 0.f, t11 = 0.f;
            float t20 = 0.f, t21 = 0.f, t30 = 0.f, t31 = 0.f;
            if (k     < n0) t00 = hs[s_bin[o0 + k]     + f];
            if (k + 1 < n0) t01 = hs[s_bin[o0 + k + 1] + f];
            if (k     < n1) t10 = hs[s_bin[o1 + k]     + f];
            if (k + 1 < n1) t11 = hs[s_bin[o1 + k + 1] + f];
            if (k     < n2) t20 = hs[s_bin[o2 + k]     + f];
            if (k + 1 < n2) t21 = hs[s_bin[o2 + k + 1] + f];
            if (k     < n3) t30 = hs[s_bin[o3 + k]     + f];
            if (k + 1 < n3) t31 = hs[s_bin[o3 + k + 1] + f];
            a0 += t00 + t01;
            a1 += t10 + t11;
            a2 += t20 + t21;
            a3 += t30 + t31;
        }
    } else {
        // fallback: direct global walk -- correctness safety net
        const unsigned int* p0 = bin + base + r0;
        const unsigned int* p1 = bin + base + r1;
        const unsigned int* p2 = bin + base + r2;
        const unsigned int* p3 = bin + base + r3;
#pragma unroll 2
        for (int k = 0; k < m; ++k) {
            if (k < n0) a0 += hs[p0[k] + f];
            if (k < n1) a1 += hs[p1[k] + f];
            if (k < n2) a2 += hs[p2[k] + f];
            if (k < n3) a3 += hs[p3[k] + f];
        }
    }
    int node0 = b << BSHIFT;
    int d0 = node0 + (int)s_perm[dd0 + 0];
    int d1 = node0 + (int)s_perm[dd0 + 1];
    int d2 = node0 + (int)s_perm[dd0 + 2];
    int d3 = node0 + (int)s_perm[dd0 + 3];
    if (d0 < N_NODES) unsafeAtomicAdd(&accG[(d0 << 4) + f], a0);
    if (d1 < N_NODES) unsafeAtomicAdd(&accG[(d1 << 4) + f], a1);
    if (d2 < N_NODES) unsafeAtomicAdd(&accG[(d2 << 4) + f], a2);
    if (d3 < N_NODES) unsafeAtomicAdd(&accG[(d3 << 4) + f], a3);
}

// out = dinv*(accG + hs_self) + bias, in place (accG aliases d_out).
template <int F, bool RELU>
__global__ void k_finish(float* __restrict__ B, float* __restrict__ accG,
                         const float* __restrict__ dinv,
                         const float* __restrict__ bias, float* __restrict__ out) {
    int i = blockIdx.x * blockDim.x + threadIdx.x;
    if (i >= N_NODES * 16) return;
    int node = i >> 4, ff = i & 15;
    float di = dinv[node];
    if (ff < F) {
        float r = di * (accG[i] + B[i]) + bias[ff];
        if (RELU) r = fmaxf(r, 0.f);
        out[node * 16 + ff] = r;
    }
}

extern "C" void kernel_launch(void* const* d_in, const int* in_sizes, int n_in,
                              void* d_out, int out_size, void* d_ws, size_t ws_size,
                              hipStream_t stream) {
    const float* x  = (const float*)d_in[0];
    const void*  ei = d_in[1];
    const float* W1 = (const float*)d_in[2];
    const float* b1 = (const float*)d_in[3];
    const float* W2 = (const float*)d_in[4];
    const float* b2 = (const float*)d_in[5];
    const float* W3 = (const float*)d_in[6];
    const float* b3 = (const float*)d_in[7];
    float* out = (float*)d_out;

    char* w = (char*)d_ws;
    int*   bucketCursor = (int*)(w + 0);        //    2048 B
    int*   flag         = (int*)(w + 2048);     //      64 B
    float* dinv         = (float*)(w + 2112);   //  800000 B
    unsigned short* seg16 = (unsigned short*)(w + 802112); // 391*2052*2 = 1604664 B
    unsigned short* permG = (unsigned short*)(w + 2406784); // 391*2048*2 = 1601536 B
    unsigned int* bin   = (unsigned int*)(w + 4008320);    // 391*18432*4 = 28827648 B
    float* B            = (float*)(w + 32835968);          // 12800000 B (N*16)
    float* accG         = out;                  // d_out doubles as accumulator
    // total ws use ~45.6 MB (proven budget: 48.8 MB in R2)

    // ---- fused init + build (q,rank)-sorted fixed-slot buckets ----
    k_init<<<12500, 256, 0, stream>>>(bucketCursor, (const unsigned int*)ei, flag, (int*)accG);
    k_binscatter<<<NCHUNK, 1024, 0, stream>>>(ei, flag, bucketCursor, bin);
    k_bucketsort<<<NBUCK, 1024, 0, stream>>>(bucketCursor, bin, dinv, seg16, permG);

    // ---- layer 1 ----
    k_xw<11, 11, 11><<<782, 256, 0, stream>>>(x, W1, dinv, B);
    k_agg<<<NBUCK * 16, 512, 0, stream>>>(seg16, permG, bin, B, accG);
    // ---- boundary 1: finish L1 + xw L2 (re-zeros accG) ----
    k_fx<11, 11><<<782, 256, 0, stream>>>(B, accG, dinv, b1, W2);
    // ---- layer 2 ----
    k_agg<<<NBUCK * 16, 512, 0, stream>>>(seg16, permG, bin, B, accG);
    // ---- boundary 2: finish L2 + xw L3 (re-zeros accG) ----
    k_fx<11, 16><<<782, 256, 0, stream>>>(B, accG, dinv, b2, W3);
    // ---- layer 3 ----
    k_agg<<<NBUCK * 16, 512, 0, stream>>>(seg16, permG, bin, B, accG);
    k_finish<16, false><<<12500, 256, 0, stream>>>(B, accG, dinv, b3, out);
}

// Round 17
// 277.423 us; speedup vs baseline: 1.2727x; 1.2727x over previous
//
#include <hip/hip_runtime.h>

#define N_NODES 200000
#define N_EDGES 6400000

constexpr int BSHIFT = 9;                      // 512 nodes per bucket
constexpr int NBUCK  = (N_NODES + 511) / 512;  // 391
constexpr int CHUNK  = 16384;
constexpr int NCHUNK = (N_EDGES + CHUNK - 1) / CHUNK;  // 391
constexpr int MAXBUCK = 18432;                 // fixed slot per bucket
constexpr int SEGSTRIDE = 2052;                // 2048 bins + end sentinel + pad
constexpr int SEGMAX = 1536;                   // staged edges per (b,Q,q); lambda=1024

// ---- edge index load helper: handles int32 or int64 storage ----
__device__ __forceinline__ int ld_edge(const void* ei, int is64, int idx) {
    return is64 ? (int)((const long long*)ei)[idx] : ((const int*)ei)[idx];
}

// fused init: zero accG (all blocks) + iota cursor + int64 detect (block 0)
__global__ void k_init(int* __restrict__ cursor, const unsigned int* __restrict__ ei,
                       int* __restrict__ flag, int* __restrict__ accG) {
    __shared__ int nz;
    int i = blockIdx.x * blockDim.x + threadIdx.x;
    if (i < N_NODES * 16) accG[i] = 0;
    if (blockIdx.x == 0) {
        int t = threadIdx.x;
        for (int j = t; j < NBUCK; j += 256) cursor[j] = j * MAXBUCK;
        if (t == 0) nz = 0;
        __syncthreads();
        if (ei[2 * t + 1] != 0u) atomicOr(&nz, 1);
        __syncthreads();
        if (t == 0) *flag = nz ? 0 : 1;
    }
}

// level-1: bin a 16K-edge chunk by dst-bucket. Each thread holds its 16
// edges in REGISTERS (static unroll) -> src/dst each read exactly once.
// Staged word packs (q<<27)|(local_dst<<18)|src; contiguous runs written
// into the bucket's FIXED slot.
__global__ void __launch_bounds__(1024)
k_binscatter(const void* __restrict__ ei, const int* __restrict__ flag,
             int* __restrict__ bucketCursor, unsigned int* __restrict__ bin) {
    __shared__ int hist[NBUCK];
    __shared__ int pref[NBUCK + 1];
    __shared__ int cur[NBUCK];
    __shared__ int gb[NBUCK];
    __shared__ int sc[512];
    __shared__ unsigned int stage[CHUNK];
    const int is64 = *flag;
    int b = blockIdx.x, t = threadIdx.x;
    int e0 = b * CHUNK;
    int n = min(CHUNK, N_EDGES - e0);
    for (int i = t; i < NBUCK; i += 1024) hist[i] = 0;
    // load my 16 edges into registers (coalesced, stride-1024)
    int sd[16], ss[16];
#pragma unroll
    for (int j = 0; j < 16; ++j) {
        int idx = t + (j << 10);
        if (idx < n) {
            ss[j] = ld_edge(ei, is64, e0 + idx);
            sd[j] = ld_edge(ei, is64, N_EDGES + e0 + idx);
        } else {
            ss[j] = -1; sd[j] = -1;
        }
    }
    __syncthreads();
    // pass A: per-chunk bucket histogram (from registers)
#pragma unroll
    for (int j = 0; j < 16; ++j)
        if (sd[j] >= 0) atomicAdd(&hist[sd[j] >> BSHIFT], 1);
    __syncthreads();
    // scan 512 entries (threads 0-255 work, all barrier)
    if (t < 256) {
        sc[t]       = (t < NBUCK)       ? hist[t]       : 0;
        sc[t + 256] = (t + 256 < NBUCK) ? hist[t + 256] : 0;
    }
    __syncthreads();
    for (int off = 1; off < 512; off <<= 1) {
        int a0 = 0, a1 = 0;
        if (t < 256) {
            a0 = (t >= off) ? sc[t - off] : 0;
            a1 = sc[t + 256 - off];
        }
        __syncthreads();
        if (t < 256) { sc[t] += a0; sc[t + 256] += a1; }
        __syncthreads();
    }
    for (int i = t; i < NBUCK; i += 1024) {
        int excl = sc[i] - hist[i];
        pref[i] = excl;
        cur[i] = excl;
    }
    if (t == 0) pref[NBUCK] = n;
    __syncthreads();
    // pass B: scatter packed (q<<27)|(local_d<<18)|src into LDS stage
#pragma unroll
    for (int j = 0; j < 16; ++j) {
        if (sd[j] >= 0) {
            int bk = sd[j] >> BSHIFT;
            unsigned int q = (unsigned int)ss[j] / 50000u;
            int p = atomicAdd(&cur[bk], 1);
            stage[p] = (q << 27) | ((unsigned int)(sd[j] & 511) << 18) | (unsigned int)ss[j];
        }
    }
    __syncthreads();
    // reserve global ranges in fixed slots, one atomic per non-empty bucket
    for (int i = t; i < NBUCK; i += 1024) {
        int c = hist[i];
        gb[i] = c ? atomicAdd(&bucketCursor[i], c) : 0;
    }
    __syncthreads();
    // write-out: wave w copies buckets w, w+16, ... (contiguous runs);
    // clamp to slot end (safety, never expected to trigger)
    int wave = t >> 6, lane = t & 63;
    for (int i = wave; i < NBUCK; i += 16) {
        int c = hist[i];
        if (!c) continue;
        int gg = gb[i];
        int room = (i + 1) * MAXBUCK - gg;
        int lim = min(c, max(room, 0));
        int pp = pref[i];
        for (int j = lane; j < lim; j += 64) bin[gg + j] = stage[pp + j];
    }
}

// level-2: one block per bucket, 1024 threads. Counting-sort the bucket's
// edges by key (q<<9)|POS where pos = strided mapping of the degree-sorted
// rank: pos = (r&3)<<7 | r>>2. Quarters get every 4th rank (BALANCED
// blocks, nseg ~1024 << SEGMAX) while a wave's 16 dsts span only ~64
// sorted ranks (near-equal degrees -> no divergence waste). Emits u16
// rowptr (by pos), perm (pos->dst), dinv. Payload: src<<4.
__global__ void __launch_bounds__(1024)
k_bucketsort(const int* __restrict__ bucketCursor, unsigned int* __restrict__ bin,
             float* __restrict__ dinv, unsigned short* __restrict__ seg16,
             unsigned short* __restrict__ permG) {
    __shared__ int cnt[2048];        // by (q<<9)|dst
    __shared__ int cntP[2048];       // by (q<<9)|pos
    __shared__ int cur[2048];        // rowptr by pos (mutated in pass B)
    __shared__ int tsum[1024];
    __shared__ int dhist[256];       // 4 q x 64 degree bins
    __shared__ unsigned short rank[2048];  // (q<<9)|dst -> pos
    __shared__ unsigned short perm[2048];  // (q<<9)|pos -> dst
    __shared__ unsigned int payload[MAXBUCK];
    int b = blockIdx.x, t = threadIdx.x;
    int base = b * MAXBUCK;
    int n = min(bucketCursor[b] - base, MAXBUCK);
    cnt[t] = 0; cnt[t + 1024] = 0;
    if (t < 256) dhist[t] = 0;
    __syncthreads();
    // pass A: histogram over 2048 (q, dst) bins
    for (int i = t; i < n; i += 1024) {
        unsigned int u = bin[base + i];
        int key = (int)((u >> 27) << 9) | (int)((u >> 18) & 511u);
        atomicAdd(&cnt[key], 1);
    }
    __syncthreads();
    // degree histogram per q (64 clamped degree bins)
    for (int i = t; i < 2048; i += 1024) {
        int dg = min(cnt[i], 63);
        atomicAdd(&dhist[((i >> 9) << 6) | dg], 1);
    }
    __syncthreads();
    // exclusive scan within each q's 64 degree bins (serial, 4 threads)
    if (t < 4) {
        int acc = 0;
        for (int j = 0; j < 64; ++j) {
            int idx = (t << 6) | j;
            int c = dhist[idx]; dhist[idx] = acc; acc += c;
        }
    }
    __syncthreads();
    // assign degree-sorted ranks; spread across quarters via strided pos
    for (int i = t; i < 2048; i += 1024) {
        int dg = min(cnt[i], 63);
        int q = i >> 9;
        int r = atomicAdd(&dhist[(q << 6) | dg], 1);
        int pos = ((r & 3) << 7) | (r >> 2);   // quarter = r&3, slot = r>>2
        rank[i] = (unsigned short)pos;
        perm[(q << 9) | pos] = (unsigned short)(i & 511);
        cntP[(q << 9) | pos] = cnt[i];
    }
    __syncthreads();
    // scan 2048 over cntP: serial-2 per thread + Hillis-Steele over 1024 sums
    int b0 = t * 2;
    int s = cntP[b0] + cntP[b0 + 1];
    tsum[t] = s;
    __syncthreads();
    int v = s;
    for (int off = 1; off < 1024; off <<= 1) {
        int add = (t >= off) ? tsum[t - off] : 0;
        __syncthreads();
        tsum[t] += add;
        __syncthreads();
    }
    int run = tsum[t] - v;  // exclusive prefix of this thread's pair
    cur[b0] = run;
    cur[b0 + 1] = run + cntP[b0];
    __syncthreads();
    // write u16 rowptr-by-pos + perm + sentinel + dinv
    for (int i = t; i < 2048; i += 1024) {
        seg16[b * SEGSTRIDE + i] = (unsigned short)cur[i];
        permG[b * 2048 + i] = perm[i];
    }
    if (t == 0) seg16[b * SEGSTRIDE + 2048] = (unsigned short)n;
    int node0 = b << BSHIFT;
    if (t < 512) {
        int node = node0 + t;
        if (node < N_NODES) {
            int deg = cnt[t] + cnt[512 + t] + cnt[1024 + t] + cnt[1536 + t];
            dinv[node] = rsqrtf((float)deg + 1.0f);
        }
    }
    __syncthreads();
    // pass B: scatter src<<4 into payload by pos-order position
    for (int i = t; i < n; i += 1024) {
        unsigned int u = bin[base + i];
        int korig = (int)((u >> 27) << 9) | (int)((u >> 18) & 511u);
        int key = (int)((u >> 27) << 9) | (int)rank[korig];
        int p = atomicAdd(&cur[key], 1);
        if (p < MAXBUCK) payload[p] = (u & 0x3FFFFu) << 4;
    }
    __syncthreads();
    // coalesced in-place write-back (sorted by (q, pos))
    for (int i = t; i < n; i += 1024) bin[base + i] = payload[i];
}

// hs = dinv[i] * (x @ W), padded to stride 16 (one 64B line per row).
template <int FIN, int FOUT, int SIN>
__global__ void k_xw(const float* xin, const float* __restrict__ W,
                     const float* __restrict__ dinv, float* hs) {
    __shared__ float sW[FIN * FOUT];
    int t = threadIdx.x;
    if (t < FIN * FOUT) sW[t] = W[t];
    __syncthreads();
    int i = blockIdx.x * 256 + t;
    if (i >= N_NODES) return;
    float xi[FIN];
#pragma unroll
    for (int k = 0; k < FIN; ++k) xi[k] = xin[i * SIN + k];
    float di = dinv[i];
    float o[FOUT];
#pragma unroll
    for (int j = 0; j < FOUT; ++j) {
        float acc = 0.f;
#pragma unroll
        for (int k = 0; k < FIN; ++k) acc += xi[k] * sW[k * FOUT + j];
        o[j] = di * acc;
    }
#pragma unroll
    for (int j = 0; j < FOUT; ++j) hs[i * 16 + j] = o[j];
}

// Fused boundary kernel: x' = relu(dinv*(accG + hs_prev) + biasPrev);
// hs_next = dinv * (x' @ Wnext) -> B. Re-zeros accG for the next layer.
template <int FIN, int FOUT>
__global__ void k_fx(float* __restrict__ B, float* __restrict__ accG,
                     const float* __restrict__ dinv,
                     const float* __restrict__ biasPrev,
                     const float* __restrict__ Wnext) {
    __shared__ float sW[FIN * FOUT];
    __shared__ float sb[FIN];
    int t = threadIdx.x;
    if (t < FIN * FOUT) sW[t] = Wnext[t];
    if (t < FIN) sb[t] = biasPrev[t];
    __syncthreads();
    int i = blockIdx.x * 256 + t;
    if (i >= N_NODES) return;
    float di = dinv[i];
    float xi[FIN];
#pragma unroll
    for (int k = 0; k < FIN; ++k) {
        float v = di * (accG[i * 16 + k] + B[i * 16 + k]) + sb[k];
        xi[k] = fmaxf(v, 0.f);
    }
#pragma unroll
    for (int c = 0; c < 16; ++c) accG[i * 16 + c] = 0.f;
    float o[FOUT];
#pragma unroll
    for (int j = 0; j < FOUT; ++j) {
        float acc = 0.f;
#pragma unroll
        for (int k = 0; k < FIN; ++k) acc += xi[k] * sW[k * FOUT + j];
        o[j] = di * acc;
    }
#pragma unroll
    for (int j = 0; j < FOUT; ++j) B[i * 16 + j] = o[j];
}

// One block per (bucket, quarter, q). q = blk&3 -> XCD-pinned 3.2 MB src
// window; bin segment staged to LDS; payload pre-shifted src<<4. Runs are
// degree-EQUALIZED within each wave (strided rank mapping) and quarters
// are balanced across blocks. Flush: node = node0 + perm[pos]; one
// unsafeAtomicAdd per dst with 16 consecutive lanes = one line RMW.
__global__ void __launch_bounds__(512)
k_agg(const unsigned short* __restrict__ seg16, const unsigned short* __restrict__ permG,
      const unsigned int* __restrict__ bin, const float* __restrict__ hs,
      float* __restrict__ accG) {
    __shared__ unsigned short s_sr[132];
    __shared__ unsigned short s_perm[128];
    __shared__ unsigned int s_bin[SEGMAX];
    int blk = blockIdx.x;
    int q = blk & 3;
    int Q = (blk >> 2) & 3;
    int b = blk >> 4;
    int t = threadIdx.x;
    int base = b * MAXBUCK;
    const unsigned short* sr = seg16 + b * SEGSTRIDE + (q << 9) + (Q << 7);
    if (t < 129) s_sr[t] = sr[t];
    if (t >= 256 && t < 384) s_perm[t - 256] = permG[b * 2048 + (q << 9) + (Q << 7) + (t - 256)];
    __syncthreads();
    int s0 = (int)s_sr[0];
    int nseg = (int)s_sr[128] - s0;
    bool staged = (nseg <= SEGMAX);
    if (staged) {
        for (int i = t; i < nseg; i += 512) s_bin[i] = bin[base + s0 + i];
    }
    __syncthreads();
    int g = t >> 4, f = t & 15;
    int dd0 = g << 2;
    int r0 = (int)s_sr[dd0 + 0], r1 = (int)s_sr[dd0 + 1], r2 = (int)s_sr[dd0 + 2];
    int r3 = (int)s_sr[dd0 + 3], r4 = (int)s_sr[dd0 + 4];
    int n0 = r1 - r0, n1 = r2 - r1, n2 = r3 - r2, n3 = r4 - r3;
    float a0 = 0.f, a1 = 0.f, a2 = 0.f, a3 = 0.f;
    int m = max(max(n0, n1), max(n2, n3));
    if (staged) {
        int o0 = r0 - s0, o1 = r1 - s0, o2 = r2 - s0, o3 = r3 - s0;
#pragma unroll 2
        for (int k = 0; k < m; k += 2) {
            float t00 = 0.f, t01 = 0.f, t10 = 0.f, t11 = 0.f;
            float t20 = 0.f, t21 = 0.f, t30 = 0.f, t31 = 0.f;
            if (k     < n0) t00 = hs[s_bin[o0 + k]     + f];
            if (k + 1 < n0) t01 = hs[s_bin[o0 + k + 1] + f];
            if (k     < n1) t10 = hs[s_bin[o1 + k]     + f];
            if (k + 1 < n1) t11 = hs[s_bin[o1 + k + 1] + f];
            if (k     < n2) t20 = hs[s_bin[o2 + k]     + f];
            if (k + 1 < n2) t21 = hs[s_bin[o2 + k + 1] + f];
            if (k     < n3) t30 = hs[s_bin[o3 + k]     + f];
            if (k + 1 < n3) t31 = hs[s_bin[o3 + k + 1] + f];
            a0 += t00 + t01;
            a1 += t10 + t11;
            a2 += t20 + t21;
            a3 += t30 + t31;
        }
    } else {
        // fallback: direct global walk -- correctness safety net
        const unsigned int* p0 = bin + base + r0;
        const unsigned int* p1 = bin + base + r1;
        const unsigned int* p2 = bin + base + r2;
        const unsigned int* p3 = bin + base + r3;
#pragma unroll 2
        for (int k = 0; k < m; ++k) {
            if (k < n0) a0 += hs[p0[k] + f];
            if (k < n1) a1 += hs[p1[k] + f];
            if (k < n2) a2 += hs[p2[k] + f];
            if (k < n3) a3 += hs[p3[k] + f];
        }
    }
    int node0 = b << BSHIFT;
    int d0 = node0 + (int)s_perm[dd0 + 0];
    int d1 = node0 + (int)s_perm[dd0 + 1];
    int d2 = node0 + (int)s_perm[dd0 + 2];
    int d3 = node0 + (int)s_perm[dd0 + 3];
    if (d0 < N_NODES) unsafeAtomicAdd(&accG[(d0 << 4) + f], a0);
    if (d1 < N_NODES) unsafeAtomicAdd(&accG[(d1 << 4) + f], a1);
    if (d2 < N_NODES) unsafeAtomicAdd(&accG[(d2 << 4) + f], a2);
    if (d3 < N_NODES) unsafeAtomicAdd(&accG[(d3 << 4) + f], a3);
}

// out = dinv*(accG + hs_self) + bias, in place (accG aliases d_out).
template <int F, bool RELU>
__global__ void k_finish(float* __restrict__ B, float* __restrict__ accG,
                         const float* __restrict__ dinv,
                         const float* __restrict__ bias, float* __restrict__ out) {
    int i = blockIdx.x * blockDim.x + threadIdx.x;
    if (i >= N_NODES * 16) return;
    int node = i >> 4, ff = i & 15;
    float di = dinv[node];
    if (ff < F) {
        float r = di * (accG[i] + B[i]) + bias[ff];
        if (RELU) r = fmaxf(r, 0.f);
        out[node * 16 + ff] = r;
    }
}

extern "C" void kernel_launch(void* const* d_in, const int* in_sizes, int n_in,
                              void* d_out, int out_size, void* d_ws, size_t ws_size,
                              hipStream_t stream) {
    const float* x  = (const float*)d_in[0];
    const void*  ei = d_in[1];
    const float* W1 = (const float*)d_in[2];
    const float* b1 = (const float*)d_in[3];
    const float* W2 = (const float*)d_in[4];
    const float* b2 = (const float*)d_in[5];
    const float* W3 = (const float*)d_in[6];
    const float* b3 = (const float*)d_in[7];
    float* out = (float*)d_out;

    char* w = (char*)d_ws;
    int*   bucketCursor = (int*)(w + 0);        //    2048 B
    int*   flag         = (int*)(w + 2048);     //      64 B
    float* dinv         = (float*)(w + 2112);   //  800000 B
    unsigned short* seg16 = (unsigned short*)(w + 802112); // 391*2052*2 = 1604664 B
    unsigned short* permG = (unsigned short*)(w + 2406784); // 391*2048*2 = 1601536 B
    unsigned int* bin   = (unsigned int*)(w + 4008320);    // 391*18432*4 = 28827648 B
    float* B            = (float*)(w + 32835968);          // 12800000 B (N*16)
    float* accG         = out;                  // d_out doubles as accumulator
    // total ws use ~45.6 MB (proven budget: 48.8 MB in R2)

    // ---- fused init + build (q,pos)-sorted fixed-slot buckets ----
    k_init<<<12500, 256, 0, stream>>>(bucketCursor, (const unsigned int*)ei, flag, (int*)accG);
    k_binscatter<<<NCHUNK, 1024, 0, stream>>>(ei, flag, bucketCursor, bin);
    k_bucketsort<<<NBUCK, 1024, 0, stream>>>(bucketCursor, bin, dinv, seg16, permG);

    // ---- layer 1 ----
    k_xw<11, 11, 11><<<782, 256, 0, stream>>>(x, W1, dinv, B);
    k_agg<<<NBUCK * 16, 512, 0, stream>>>(seg16, permG, bin, B, accG);
    // ---- boundary 1: finish L1 + xw L2 (re-zeros accG) ----
    k_fx<11, 11><<<782, 256, 0, stream>>>(B, accG, dinv, b1, W2);
    // ---- layer 2 ----
    k_agg<<<NBUCK * 16, 512, 0, stream>>>(seg16, permG, bin, B, accG);
    // ---- boundary 2: finish L2 + xw L3 (re-zeros accG) ----
    k_fx<11, 16><<<782, 256, 0, stream>>>(B, accG, dinv, b2, W3);
    // ---- layer 3 ----
    k_agg<<<NBUCK * 16, 512, 0, stream>>>(seg16, permG, bin, B, accG);
    k_finish<16, false><<<12500, 256, 0, stream>>>(B, accG, dinv, b3, out);
}